// Round 3
// baseline (2901.569 us; speedup 1.0000x reference)
//
#include <hip/hip_runtime.h>

#define N_POINTS 100000
#define N_PAIRS  50000
#define K_OFFSETS 27
#define C 128
#define WPAD 136   // fallback conv LDS row stride

// fused tile-stationary conv: one block owns TILE output points, accum in LDS fp32
#define TILE 128
#define NT 782             // ceil(100000/128); last tile has 32 points
#define TK_CAP 128         // entries per (tile,k); Poisson(64), 8 sigma
#define ACCW 132           // accum row stride in words: (lo*132)%32 varies -> spreads ds_add banks

// XCD-partitioned (tile,k) CSR build (round-2 proven pattern)
#define CSR_GROUPS 8
#define CSR_BPG 128
#define TPG 98             // tiles per group; 98*8 = 784 >= 782

typedef __attribute__((ext_vector_type(8))) short short8;
typedef __attribute__((ext_vector_type(4))) float floatx4;

__device__ inline unsigned short f2bf(float f) {
  unsigned int u = __float_as_uint(f);
  return (unsigned short)((u + 0x7FFFu + ((u >> 16) & 1u)) >> 16);  // RNE
}

// WT[k][d*C + c] = bf16(W[k][c][d])  -- natural order for BOTH layers
__global__ __launch_bounds__(256) void prep_w_kernel(
    const float* __restrict__ W0, const float* __restrict__ W1,
    unsigned short* __restrict__ WT0, unsigned short* __restrict__ WT1) {
  int i = blockIdx.x * 256 + threadIdx.x;
  const int per = K_OFFSETS * C * C;
  if (i >= 2 * per) return;
  const float* W = (i < per) ? W0 : W1;
  unsigned short* WT = (i < per) ? WT0 : WT1;
  int r = (i < per) ? i : i - per;
  int k = r / (C * C);
  int q = r % (C * C);
  int d = q / C;
  int c = q % C;
  WT[k * C * C + d * C + c] = f2bf(W[k * C * C + c * C + d]);
}

// xb = bf16(features); out = broadcast(b0) only on the fallback path
__global__ __launch_bounds__(256) void prep_x_kernel(
    const float* __restrict__ features, const float* __restrict__ b0,
    unsigned short* __restrict__ xb, float* __restrict__ out, int write_out) {
  int i = (blockIdx.x * 256 + threadIdx.x) * 4;
  if (i >= N_POINTS * C) return;
  float4 f = *(const float4*)&features[i];
  ushort4 u;
  u.x = f2bf(f.x); u.y = f2bf(f.y); u.z = f2bf(f.z); u.w = f2bf(f.w);
  *(ushort4*)&xb[i] = u;
  if (write_out) {
    float4 b = *(const float4*)&b0[i & 127];
    *(float4*)&out[i] = b;
  }
}

__global__ __launch_bounds__(256) void zero_cnt2_kernel(int* __restrict__ cnt2) {
  int i = blockIdx.x * 256 + threadIdx.x;
  if (i < NT * K_OFFSETS) cnt2[i] = 0;
}

// (tile,k) CSR: entry = (local_o << 17) | in_idx  (7 + 17 bits; in_idx < 2^17).
// in_map indirection resolved at build time (coalesced int4 read here).
// XCD-partitioned over tile ranges: each group's counters + bucket lines are
// touched by ONE XCD only -> write working set ~1 MB per L2, no line thrash.
__global__ __launch_bounds__(256) void build_tk_kernel(
    const int* __restrict__ out_map, const int* __restrict__ in_map,
    int* __restrict__ cnt2, int* __restrict__ idx2) {
  const int grp = blockIdx.x & (CSR_GROUPS - 1);
  const int blk = blockIdx.x >> 3;
  const int tlo = grp * TPG;
  const int thi = (tlo + TPG < NT) ? (tlo + TPG) : NT;
  const int total4 = K_OFFSETS * N_PAIRS / 4;   // 337500
  for (int i4 = blk * 256 + (int)threadIdx.x; i4 < total4; i4 += CSR_BPG * 256) {
    int4 o4 = *(const int4*)&out_map[i4 * 4];
    int4 n4 = *(const int4*)&in_map[i4 * 4];
    int o[4] = {o4.x, o4.y, o4.z, o4.w};
    int n[4] = {n4.x, n4.y, n4.z, n4.w};
#pragma unroll
    for (int j = 0; j < 4; ++j) {
      int tt = o[j] >> 7;
      if (tt >= tlo && tt < thi) {
        int flat = i4 * 4 + j;
        int k = flat / N_PAIRS;
        int pos = atomicAdd(&cnt2[tt * K_OFFSETS + k], 1);
        if (pos < TK_CAP)
          idx2[(tt * K_OFFSETS + k) * TK_CAP + pos] = ((o[j] & 127) << 17) | n[j];
      }
    }
  }
}

// Fused conv+scatter, output-tile-stationary. Block = 128-point tile.
// Per k: stage entry list (<=128), gather x rows (A-frags, same addressing as
// the proven conv_msg), W B-frags read straight from L2-resident WT global,
// MFMA 16x16x32, scatter D-frags into LDS fp32 accum via ds_add_f32.
// D mapping (verified by 2 sessions of conv_msg): value acc[nt][i] belongs to
// (entry = kg*4+i within row-tile, chan = nt*16 + l15).
// Epilogue: layer 0 -> x1b = bf16(relu(acc+b0)); layer 1 -> out = acc+b1+features.
// LDS 68.1 KB -> 2 blocks/CU (8 waves). No inter-block races: tile owns its points.
__global__ __launch_bounds__(256, 2) void fused_conv_kernel(
    const unsigned short* __restrict__ xb, const unsigned short* __restrict__ wbt,
    const int* __restrict__ cnt2, const int* __restrict__ idx2,
    const float* __restrict__ bias, const float* __restrict__ features,
    float* __restrict__ out, unsigned short* __restrict__ x1b, int layer) {
  __shared__ float accum[TILE * ACCW];   // 67,584 B
  __shared__ int lk[TK_CAP];             //    512 B

  const int t = blockIdx.x;
  const int tid = threadIdx.x;
  const int wave = tid >> 6;
  const int lane = tid & 63;
  const int l15 = lane & 15;
  const int kg = lane >> 4;

  for (int i = tid; i < TILE * ACCW; i += 256) accum[i] = 0.f;

  for (int k = 0; k < K_OFFSETS; ++k) {
    __syncthreads();                       // accum zero / prev-k reads done
    const int b = t * K_OFFSETS + k;
    if (tid < TK_CAP) lk[tid] = idx2[b * TK_CAP + tid];
    __syncthreads();
    int e = cnt2[b]; if (e > TK_CAP) e = TK_CAP;
    if (e == 0) continue;                  // uniform branch (e same for all)
    const int nrt = (e + 15) >> 4;
    const unsigned short* wk = wbt + k * C * C + l15 * C + kg * 8;
    for (int rt = wave; rt < nrt; rt += 4) {
      int er = rt * 16 + l15;
      int epk = lk[(er < e) ? er : 0];     // clamp: garbage rows predicated at scatter
      const unsigned short* xrow = xb + (size_t)(epk & 0x1FFFF) * C + kg * 8;
      floatx4 acc[8];
#pragma unroll
      for (int nt = 0; nt < 8; ++nt) acc[nt] = (floatx4){0.f, 0.f, 0.f, 0.f};
#pragma unroll
      for (int kk = 0; kk < 4; ++kk) {
        short8 a = *(const short8*)(xrow + kk * 32);
        const unsigned short* bb = wk + kk * 32;
#pragma unroll
        for (int nt = 0; nt < 8; ++nt) {
          short8 bv = *(const short8*)(bb + nt * 16 * C);
          acc[nt] = __builtin_amdgcn_mfma_f32_16x16x32_bf16(a, bv, acc[nt], 0, 0, 0);
        }
      }
#pragma unroll
      for (int i = 0; i < 4; ++i) {
        int ei = rt * 16 + kg * 4 + i;
        if (ei < e) {
          int lo = ((unsigned int)lk[ei]) >> 17;
          float* ar = &accum[lo * ACCW + l15];
#pragma unroll
          for (int nt = 0; nt < 8; ++nt)
            atomicAdd(ar + nt * 16, acc[nt][i]);   // ds_add_f32
        }
      }
    }
  }
  __syncthreads();

  // epilogue: col fixed per thread (256 % 128 == 0), 64 rows x 2 threads-per-row
  const int col = tid & 127;
  const float bv = bias[col];
  const int r0 = tid >> 7;
#pragma unroll 4
  for (int j = 0; j < TILE / 2; ++j) {
    int row = r0 + j * 2;
    int o = t * TILE + row;
    if (o < N_POINTS) {
      float v = accum[row * ACCW + col] + bv;
      if (layer == 0) {
        x1b[(size_t)o * C + col] = f2bf(fmaxf(v, 0.f));
      } else {
        out[(size_t)o * C + col] = v + features[(size_t)o * C + col];
      }
    }
  }
}

// ---------------- fallback (atomic path, <53 MB ws, natural WT) ----------------
__global__ __launch_bounds__(256) void mid_kernel(
    const float* __restrict__ features, const float* __restrict__ b1,
    float* __restrict__ out, unsigned short* __restrict__ x1b) {
  int i = (blockIdx.x * 256 + threadIdx.x) * 4;
  if (i >= N_POINTS * C) return;
  float4 y = *(const float4*)&out[i];
  ushort4 u;
  u.x = f2bf(fmaxf(y.x, 0.f));
  u.y = f2bf(fmaxf(y.y, 0.f));
  u.z = f2bf(fmaxf(y.z, 0.f));
  u.w = f2bf(fmaxf(y.w, 0.f));
  *(ushort4*)&x1b[i] = u;
  float4 f = *(const float4*)&features[i];
  float4 b = *(const float4*)&b1[i & 127];
  float4 o;
  o.x = f.x + b.x; o.y = f.y + b.y; o.z = f.z + b.z; o.w = f.w + b.w;
  *(float4*)&out[i] = o;
}

__global__ __launch_bounds__(256, 4) void conv_atomic_kernel(
    const unsigned short* __restrict__ xb, const unsigned short* __restrict__ wbt,
    const int* __restrict__ in_map, const int* __restrict__ out_map,
    float* __restrict__ out) {
  __shared__ unsigned short Wlds[C * WPAD];
  const int k = blockIdx.y;
  const int pairBase = blockIdx.x * 64;
  const int tid = threadIdx.x;
  const unsigned short* wk = wbt + k * C * C;
#pragma unroll
  for (int it = 0; it < 8; ++it) {
    int t = tid + it * 256;
    int row = t >> 4;
    int col = (t & 15) << 3;
    *(uint4*)&Wlds[row * WPAD + col] = *(const uint4*)&wk[row * C + col];
  }
  __syncthreads();
  const int wave = tid >> 6;
  const int lane = tid & 63;
  const int l15 = lane & 15;
  const int kg = lane >> 4;
  const int pair0 = pairBase + wave * 16;
  const int prA = pair0 + l15;
  const int inIdx = (prA < N_PAIRS) ? in_map[k * N_PAIRS + prA] : 0;
  const unsigned short* arow = xb + (size_t)inIdx * C + kg * 8;
  floatx4 acc[8];
#pragma unroll
  for (int nt = 0; nt < 8; ++nt) acc[nt] = (floatx4){0.f, 0.f, 0.f, 0.f};
#pragma unroll
  for (int kk = 0; kk < 4; ++kk) {
    short8 a = *(const short8*)(arow + kk * 32);
    const unsigned short* bbase = &Wlds[l15 * WPAD + kk * 32 + kg * 8];
#pragma unroll
    for (int nt = 0; nt < 8; ++nt) {
      short8 b = *(const short8*)(bbase + nt * 16 * WPAD);
      acc[nt] = __builtin_amdgcn_mfma_f32_16x16x32_bf16(a, b, acc[nt], 0, 0, 0);
    }
  }
#pragma unroll
  for (int i = 0; i < 4; ++i) {
    int pr = pair0 + kg * 4 + i;
    if (pr < N_PAIRS) {
      int oi = out_map[k * N_PAIRS + pr];
      float* orow = out + (size_t)oi * C + l15;
#pragma unroll
      for (int nt = 0; nt < 8; ++nt) atomicAdd(orow + nt * 16, acc[nt][i]);
    }
  }
}

extern "C" void kernel_launch(void* const* d_in, const int* in_sizes, int n_in,
                              void* d_out, int out_size, void* d_ws, size_t ws_size,
                              hipStream_t stream) {
  const float* features = (const float*)d_in[0];
  const int* in_map     = (const int*)d_in[1];
  const int* out_map    = (const int*)d_in[2];
  const float* W0       = (const float*)d_in[3];
  const float* b0       = (const float*)d_in[4];
  const float* W1       = (const float*)d_in[5];
  const float* b1       = (const float*)d_in[6];
  float* out = (float*)d_out;

  char* ws = (char*)d_ws;
  unsigned short* xb  = (unsigned short*)(ws);                  // 25,600,000
  unsigned short* x1b = (unsigned short*)(ws + 25600000);       // 25,600,000
  unsigned short* WT0 = (unsigned short*)(ws + 51200000);       //    884,736
  unsigned short* WT1 = (unsigned short*)(ws + 52084736);       //    884,736
  int* cnt2           = (int*)(ws + 52969472);                  //     84,456 (782*27*4)
  int* idx2           = (int*)(ws + 53053952);                  // 10,810,368 (782*27*128*4)
  // end = 63,864,320

  const int use_fused = (ws_size >= 63864320ULL) ? 1 : 0;

  prep_w_kernel<<<(2 * K_OFFSETS * C * C + 255) / 256, 256, 0, stream>>>(W0, W1, WT0, WT1);
  prep_x_kernel<<<(N_POINTS * C / 4 + 255) / 256, 256, 0, stream>>>(
      features, b0, xb, out, use_fused ? 0 : 1);

  if (use_fused) {
    zero_cnt2_kernel<<<(NT * K_OFFSETS + 255) / 256, 256, 0, stream>>>(cnt2);
    build_tk_kernel<<<CSR_GROUPS * CSR_BPG, 256, 0, stream>>>(out_map, in_map, cnt2, idx2);

    fused_conv_kernel<<<NT, 256, 0, stream>>>(
        xb, WT0, cnt2, idx2, b0, features, out, x1b, 0);
    fused_conv_kernel<<<NT, 256, 0, stream>>>(
        x1b, WT1, cnt2, idx2, b1, features, out, x1b, 1);
  } else {
    dim3 cgrid((N_PAIRS + 63) / 64, K_OFFSETS);
    conv_atomic_kernel<<<cgrid, 256, 0, stream>>>(xb, WT0, in_map, out_map, out);
    mid_kernel<<<(N_POINTS * C / 4 + 255) / 256, 256, 0, stream>>>(features, b1, out, x1b);
    conv_atomic_kernel<<<cgrid, 256, 0, stream>>>(x1b, WT1, in_map, out_map, out);
  }
}

// Round 4
// 2256.048 us; speedup vs baseline: 1.2861x; 1.2861x over previous
//
#include <hip/hip_runtime.h>

#define N_POINTS 100000
#define N_PAIRS  50000
#define K_OFFSETS 27
#define C 128
#define WPAD 136   // fallback conv LDS row stride

// fused tile-stationary conv v2: TILE=64, flat barrier-free supertile worklist
#define TILE 64
#define NT 1563            // ceil(100000/64)
#define TK_CAP 96          // entries per (tile,k); Poisson(32), +11 sigma
#define ACCW 132           // accum row stride (words); lo*4 mod 32 spreads ds_add banks
#define MAXST 96           // max supertiles per tile (27*3 = 81)

// XCD-partitioned (tile,k) CSR build (round-2 proven pattern)
#define CSR_GROUPS 8
#define CSR_BPG 128
#define TPG 196            // tiles per group; 196*8 = 1568 >= 1563

typedef __attribute__((ext_vector_type(8))) short short8;
typedef __attribute__((ext_vector_type(4))) float floatx4;

__device__ inline unsigned short f2bf(float f) {
  unsigned int u = __float_as_uint(f);
  return (unsigned short)((u + 0x7FFFu + ((u >> 16) & 1u)) >> 16);  // RNE
}

// WT[k][d*C + c] = bf16(W[k][c][d])  -- natural order for BOTH layers
__global__ __launch_bounds__(256) void prep_w_kernel(
    const float* __restrict__ W0, const float* __restrict__ W1,
    unsigned short* __restrict__ WT0, unsigned short* __restrict__ WT1) {
  int i = blockIdx.x * 256 + threadIdx.x;
  const int per = K_OFFSETS * C * C;
  if (i >= 2 * per) return;
  const float* W = (i < per) ? W0 : W1;
  unsigned short* WT = (i < per) ? WT0 : WT1;
  int r = (i < per) ? i : i - per;
  int k = r / (C * C);
  int q = r % (C * C);
  int d = q / C;
  int c = q % C;
  WT[k * C * C + d * C + c] = f2bf(W[k * C * C + c * C + d]);
}

// xb = bf16(features); out = broadcast(b0) only on the fallback path
__global__ __launch_bounds__(256) void prep_x_kernel(
    const float* __restrict__ features, const float* __restrict__ b0,
    unsigned short* __restrict__ xb, float* __restrict__ out, int write_out) {
  int i = (blockIdx.x * 256 + threadIdx.x) * 4;
  if (i >= N_POINTS * C) return;
  float4 f = *(const float4*)&features[i];
  ushort4 u;
  u.x = f2bf(f.x); u.y = f2bf(f.y); u.z = f2bf(f.z); u.w = f2bf(f.w);
  *(ushort4*)&xb[i] = u;
  if (write_out) {
    float4 b = *(const float4*)&b0[i & 127];
    *(float4*)&out[i] = b;
  }
}

__global__ __launch_bounds__(256) void zero_cnt2_kernel(int* __restrict__ cnt2) {
  int i = blockIdx.x * 256 + threadIdx.x;
  if (i < NT * K_OFFSETS) cnt2[i] = 0;
}

// (tile,k) CSR: entry = (local_o << 17) | in_idx  (6 + 17 bits).
// in_map indirection resolved at build time. XCD-partitioned over tile ranges
// so each group's counter/bucket lines live in ONE XCD's L2 (round-2 proven).
__global__ __launch_bounds__(256) void build_tk_kernel(
    const int* __restrict__ out_map, const int* __restrict__ in_map,
    int* __restrict__ cnt2, int* __restrict__ idx2) {
  const int grp = blockIdx.x & (CSR_GROUPS - 1);
  const int blk = blockIdx.x >> 3;
  const int tlo = grp * TPG;
  const int thi = (tlo + TPG < NT) ? (tlo + TPG) : NT;
  const int total4 = K_OFFSETS * N_PAIRS / 4;   // 337500
  for (int i4 = blk * 256 + (int)threadIdx.x; i4 < total4; i4 += CSR_BPG * 256) {
    int4 o4 = *(const int4*)&out_map[i4 * 4];
    int4 n4 = *(const int4*)&in_map[i4 * 4];
    int o[4] = {o4.x, o4.y, o4.z, o4.w};
    int n[4] = {n4.x, n4.y, n4.z, n4.w};
#pragma unroll
    for (int j = 0; j < 4; ++j) {
      int tt = o[j] >> 6;
      if (tt >= tlo && tt < thi) {
        int flat = i4 * 4 + j;
        int k = flat / N_PAIRS;
        int pos = atomicAdd(&cnt2[tt * K_OFFSETS + k], 1);
        if (pos < TK_CAP)
          idx2[(tt * K_OFFSETS + k) * TK_CAP + pos] = ((o[j] & 63) << 17) | n[j];
      }
    }
  }
}

// Fused conv+scatter v2. Block = 64-point tile, fp32 accum in LDS (33.8 KB).
// Startup: prefix-scan the 27 bucket counts into a flat list of 32-entry
// supertiles (k-tagged). Main loop: waves grab supertiles round-robin with NO
// barriers; per supertile: 2 A-tiles (16 rows each, conv_msg-proven pairing)
// share streamed B-frags from L2-resident WT; D scattered into accum via
// ds_add_f32 using the round-3-verified mapping (entry=kg*4+i, chan=nt*16+l15).
// Scatter row index comes from __shfl of the already-loaded entry regs.
__global__ __launch_bounds__(256, 3) void fused_conv_kernel(
    const unsigned short* __restrict__ xb, const unsigned short* __restrict__ wbt,
    const int* __restrict__ cnt2, const int* __restrict__ idx2,
    const float* __restrict__ bias, const float* __restrict__ features,
    float* __restrict__ out, unsigned short* __restrict__ x1b, int layer) {
  __shared__ float accum[TILE * ACCW];          // 33,792 B
  __shared__ int ecnt[K_OFFSETS];
  __shared__ int stbase[K_OFFSETS + 1];
  __shared__ int stk[MAXST];

  const int t = blockIdx.x;
  const int tid = threadIdx.x;
  const int wave = tid >> 6;
  const int lane = tid & 63;
  const int l15 = lane & 15;
  const int kg = lane >> 4;

  for (int i = tid; i < TILE * ACCW; i += 256) accum[i] = 0.f;
  if (tid < K_OFFSETS) {
    int e = cnt2[t * K_OFFSETS + tid];
    ecnt[tid] = (e > TK_CAP) ? TK_CAP : e;
  }
  __syncthreads();
  if (tid == 0) {
    int run = 0;
    for (int k = 0; k < K_OFFSETS; ++k) {
      stbase[k] = run;
      run += (ecnt[k] + 31) >> 5;
    }
    stbase[K_OFFSETS] = run;
  }
  __syncthreads();
  if (tid < K_OFFSETS) {
    int s0 = stbase[tid];
    int nloc = stbase[tid + 1] - s0;
    for (int j = 0; j < nloc; ++j) stk[s0 + j] = (tid << 2) | j;
  }
  __syncthreads();
  const int nst = stbase[K_OFFSETS];

  for (int st = wave; st < nst; st += 4) {
    const int se = stk[st];
    const int k = se >> 2;
    const int r = se & 3;
    const int e = ecnt[k];
    const int bucket = (t * K_OFFSETS + k) * TK_CAP;
    const int i0 = r * 32 + l15;
    const int i1 = i0 + 16;
    const int ent0 = idx2[bucket + ((i0 < e) ? i0 : 0)];   // clamp: scatter predicated
    const int ent1 = idx2[bucket + ((i1 < e) ? i1 : 0)];
    const unsigned short* xrow0 = xb + (size_t)(ent0 & 0x1FFFF) * C + kg * 8;
    const unsigned short* xrow1 = xb + (size_t)(ent1 & 0x1FFFF) * C + kg * 8;

    short8 a0[4], a1[4];
#pragma unroll
    for (int kk = 0; kk < 4; ++kk) {                        // 8 loads in flight
      a0[kk] = *(const short8*)(xrow0 + kk * 32);
      a1[kk] = *(const short8*)(xrow1 + kk * 32);
    }

    const unsigned short* wk = wbt + (size_t)k * C * C + l15 * C + kg * 8;
    floatx4 acc0[8], acc1[8];
#pragma unroll
    for (int nt = 0; nt < 8; ++nt) {
      acc0[nt] = (floatx4){0.f, 0.f, 0.f, 0.f};
      acc1[nt] = (floatx4){0.f, 0.f, 0.f, 0.f};
    }
#pragma unroll
    for (int kk = 0; kk < 4; ++kk) {
      const unsigned short* bb = wk + kk * 32;
#pragma unroll
      for (int nh = 0; nh < 4; ++nh) {                      // B streamed 2-at-a-time
        short8 b0 = *(const short8*)(bb + (2 * nh) * 16 * C);
        short8 b1 = *(const short8*)(bb + (2 * nh + 1) * 16 * C);
        acc0[2 * nh]     = __builtin_amdgcn_mfma_f32_16x16x32_bf16(a0[kk], b0, acc0[2 * nh], 0, 0, 0);
        acc1[2 * nh]     = __builtin_amdgcn_mfma_f32_16x16x32_bf16(a1[kk], b0, acc1[2 * nh], 0, 0, 0);
        acc0[2 * nh + 1] = __builtin_amdgcn_mfma_f32_16x16x32_bf16(a0[kk], b1, acc0[2 * nh + 1], 0, 0, 0);
        acc1[2 * nh + 1] = __builtin_amdgcn_mfma_f32_16x16x32_bf16(a1[kk], b1, acc1[2 * nh + 1], 0, 0, 0);
      }
    }

#pragma unroll
    for (int i = 0; i < 4; ++i) {
      const int sl = kg * 4 + i;
      const int le0 = __shfl(ent0, sl);
      const int le1 = __shfl(ent1, sl);
      const int ei0 = r * 32 + sl;
      const int ei1 = ei0 + 16;
      if (ei0 < e) {
        float* ar = &accum[(((unsigned int)le0) >> 17) * ACCW + l15];
#pragma unroll
        for (int nt = 0; nt < 8; ++nt) atomicAdd(ar + nt * 16, acc0[nt][i]);
      }
      if (ei1 < e) {
        float* ar = &accum[(((unsigned int)le1) >> 17) * ACCW + l15];
#pragma unroll
        for (int nt = 0; nt < 8; ++nt) atomicAdd(ar + nt * 16, acc1[nt][i]);
      }
    }
  }
  __syncthreads();

  // epilogue: col fixed per thread, 2 rows in flight, 32 j-steps
  const int col = tid & 127;
  const float bv = bias[col];
  const int r0 = tid >> 7;
#pragma unroll 4
  for (int j = 0; j < TILE / 2; ++j) {
    int row = r0 + j * 2;
    int o = t * TILE + row;
    if (o < N_POINTS) {
      float v = accum[row * ACCW + col] + bv;
      if (layer == 0) {
        x1b[(size_t)o * C + col] = f2bf(fmaxf(v, 0.f));
      } else {
        out[(size_t)o * C + col] = v + features[(size_t)o * C + col];
      }
    }
  }
}

// ---------------- fallback (atomic path, small ws, natural WT) ----------------
__global__ __launch_bounds__(256) void mid_kernel(
    const float* __restrict__ features, const float* __restrict__ b1,
    float* __restrict__ out, unsigned short* __restrict__ x1b) {
  int i = (blockIdx.x * 256 + threadIdx.x) * 4;
  if (i >= N_POINTS * C) return;
  float4 y = *(const float4*)&out[i];
  ushort4 u;
  u.x = f2bf(fmaxf(y.x, 0.f));
  u.y = f2bf(fmaxf(y.y, 0.f));
  u.z = f2bf(fmaxf(y.z, 0.f));
  u.w = f2bf(fmaxf(y.w, 0.f));
  *(ushort4*)&x1b[i] = u;
  float4 f = *(const float4*)&features[i];
  float4 b = *(const float4*)&b1[i & 127];
  float4 o;
  o.x = f.x + b.x; o.y = f.y + b.y; o.z = f.z + b.z; o.w = f.w + b.w;
  *(float4*)&out[i] = o;
}

__global__ __launch_bounds__(256, 4) void conv_atomic_kernel(
    const unsigned short* __restrict__ xb, const unsigned short* __restrict__ wbt,
    const int* __restrict__ in_map, const int* __restrict__ out_map,
    float* __restrict__ out) {
  __shared__ unsigned short Wlds[C * WPAD];
  const int k = blockIdx.y;
  const int pairBase = blockIdx.x * 64;
  const int tid = threadIdx.x;
  const unsigned short* wk = wbt + k * C * C;
#pragma unroll
  for (int it = 0; it < 8; ++it) {
    int t = tid + it * 256;
    int row = t >> 4;
    int col = (t & 15) << 3;
    *(uint4*)&Wlds[row * WPAD + col] = *(const uint4*)&wk[row * C + col];
  }
  __syncthreads();
  const int wave = tid >> 6;
  const int lane = tid & 63;
  const int l15 = lane & 15;
  const int kg = lane >> 4;
  const int pair0 = pairBase + wave * 16;
  const int prA = pair0 + l15;
  const int inIdx = (prA < N_PAIRS) ? in_map[k * N_PAIRS + prA] : 0;
  const unsigned short* arow = xb + (size_t)inIdx * C + kg * 8;
  floatx4 acc[8];
#pragma unroll
  for (int nt = 0; nt < 8; ++nt) acc[nt] = (floatx4){0.f, 0.f, 0.f, 0.f};
#pragma unroll
  for (int kk = 0; kk < 4; ++kk) {
    short8 a = *(const short8*)(arow + kk * 32);
    const unsigned short* bbase = &Wlds[l15 * WPAD + kk * 32 + kg * 8];
#pragma unroll
    for (int nt = 0; nt < 8; ++nt) {
      short8 b = *(const short8*)(bbase + nt * 16 * WPAD);
      acc[nt] = __builtin_amdgcn_mfma_f32_16x16x32_bf16(a, b, acc[nt], 0, 0, 0);
    }
  }
#pragma unroll
  for (int i = 0; i < 4; ++i) {
    int pr = pair0 + kg * 4 + i;
    if (pr < N_PAIRS) {
      int oi = out_map[k * N_PAIRS + pr];
      float* orow = out + (size_t)oi * C + l15;
#pragma unroll
      for (int nt = 0; nt < 8; ++nt) atomicAdd(orow + nt * 16, acc[nt][i]);
    }
  }
}

extern "C" void kernel_launch(void* const* d_in, const int* in_sizes, int n_in,
                              void* d_out, int out_size, void* d_ws, size_t ws_size,
                              hipStream_t stream) {
  const float* features = (const float*)d_in[0];
  const int* in_map     = (const int*)d_in[1];
  const int* out_map    = (const int*)d_in[2];
  const float* W0       = (const float*)d_in[3];
  const float* b0       = (const float*)d_in[4];
  const float* W1       = (const float*)d_in[5];
  const float* b1       = (const float*)d_in[6];
  float* out = (float*)d_out;

  char* ws = (char*)d_ws;
  unsigned short* xb  = (unsigned short*)(ws);                  // 25,600,000
  unsigned short* x1b = (unsigned short*)(ws + 25600000);       // 25,600,000
  unsigned short* WT0 = (unsigned short*)(ws + 51200000);       //    884,736
  unsigned short* WT1 = (unsigned short*)(ws + 52084736);       //    884,736
  int* cnt2           = (int*)(ws + 52969472);                  //    168,832 (42201*4 padded)
  int* idx2           = (int*)(ws + 53138304);                  // 16,205,184 (42201*96*4)
  // end = 69,343,488

  const int use_fused = (ws_size >= 69343488ULL) ? 1 : 0;

  prep_w_kernel<<<(2 * K_OFFSETS * C * C + 255) / 256, 256, 0, stream>>>(W0, W1, WT0, WT1);
  prep_x_kernel<<<(N_POINTS * C / 4 + 255) / 256, 256, 0, stream>>>(
      features, b0, xb, out, use_fused ? 0 : 1);

  if (use_fused) {
    zero_cnt2_kernel<<<(NT * K_OFFSETS + 255) / 256, 256, 0, stream>>>(cnt2);
    build_tk_kernel<<<CSR_GROUPS * CSR_BPG, 256, 0, stream>>>(out_map, in_map, cnt2, idx2);

    fused_conv_kernel<<<NT, 256, 0, stream>>>(
        xb, WT0, cnt2, idx2, b0, features, out, x1b, 0);
    fused_conv_kernel<<<NT, 256, 0, stream>>>(
        x1b, WT1, cnt2, idx2, b1, features, out, x1b, 1);
  } else {
    dim3 cgrid((N_PAIRS + 63) / 64, K_OFFSETS);
    conv_atomic_kernel<<<cgrid, 256, 0, stream>>>(xb, WT0, in_map, out_map, out);
    mid_kernel<<<(N_POINTS * C / 4 + 255) / 256, 256, 0, stream>>>(features, b1, out, x1b);
    conv_atomic_kernel<<<cgrid, 256, 0, stream>>>(x1b, WT1, in_map, out_map, out);
  }
}

// Round 5
// 2250.544 us; speedup vs baseline: 1.2893x; 1.0024x over previous
//
#include <hip/hip_runtime.h>

#define N_POINTS 100000
#define N_PAIRS  50000
#define K_OFFSETS 27
#define C 128
#define WPAD 136   // fallback conv LDS row stride

// fused tile-stationary conv v3: TILE=64, barrier-free supertile worklist,
// W pre-swizzled to fragment-line order (1KB coalesced per B-frag load)
#define TILE 64
#define NT 1563            // ceil(100000/64)
#define TK_CAP 96          // entries per (tile,k); Poisson(32), +11 sigma
#define ACCW 132           // accum row stride (words); lo*4 mod 32 spreads ds_add banks
#define MAXST 96           // max supertiles per tile (27*3 = 81)

// XCD-partitioned (tile,k) CSR build (round-2 proven pattern)
#define CSR_GROUPS 8
#define CSR_BPG 128
#define TPG 196            // tiles per group; 196*8 = 1568 >= 1563

typedef __attribute__((ext_vector_type(8))) short short8;
typedef __attribute__((ext_vector_type(4))) float floatx4;

__device__ inline unsigned short f2bf(float f) {
  unsigned int u = __float_as_uint(f);
  return (unsigned short)((u + 0x7FFFu + ((u >> 16) & 1u)) >> 16);  // RNE
}

// mode 0 (fallback): WT[k][d*C + c] = bf16(W[k][c][d])   (natural, for LDS stage)
// mode 1 (fused):    WF[k][f][lane][j] fragment-line order, f = kk*8 + nt:
//   d = nt*16 + (lane&15), c = kk*32 + (lane>>4)*8 + j
//   -> a wave B-frag load (16B/lane) is ONE consecutive 1KB segment.
__global__ __launch_bounds__(256) void prep_w_kernel(
    const float* __restrict__ W0, const float* __restrict__ W1,
    unsigned short* __restrict__ WT0, unsigned short* __restrict__ WT1, int mode) {
  int i = blockIdx.x * 256 + threadIdx.x;
  const int per = K_OFFSETS * C * C;
  if (i >= 2 * per) return;
  const float* W = (i < per) ? W0 : W1;
  unsigned short* WT = (i < per) ? WT0 : WT1;
  int r = (i < per) ? i : i - per;
  int k = r / (C * C);
  int q = r % (C * C);
  if (mode == 0) {
    int d = q / C;
    int c = q % C;
    WT[k * C * C + d * C + c] = f2bf(W[k * C * C + c * C + d]);
  } else {
    int f = q >> 9;            // 0..31  (kk*8 + nt)
    int l = (q >> 3) & 63;     // lane
    int j = q & 7;
    int nt = f & 7;
    int kk = f >> 3;
    int d = nt * 16 + (l & 15);
    int c = kk * 32 + (l >> 4) * 8 + j;
    WT[k * C * C + q] = f2bf(W[k * C * C + c * C + d]);
  }
}

// xb = bf16(features); out = broadcast(b0) only on the fallback path
__global__ __launch_bounds__(256) void prep_x_kernel(
    const float* __restrict__ features, const float* __restrict__ b0,
    unsigned short* __restrict__ xb, float* __restrict__ out, int write_out) {
  int i = (blockIdx.x * 256 + threadIdx.x) * 4;
  if (i >= N_POINTS * C) return;
  float4 f = *(const float4*)&features[i];
  ushort4 u;
  u.x = f2bf(f.x); u.y = f2bf(f.y); u.z = f2bf(f.z); u.w = f2bf(f.w);
  *(ushort4*)&xb[i] = u;
  if (write_out) {
    float4 b = *(const float4*)&b0[i & 127];
    *(float4*)&out[i] = b;
  }
}

__global__ __launch_bounds__(256) void zero_cnt2_kernel(int* __restrict__ cnt2) {
  int i = blockIdx.x * 256 + threadIdx.x;
  if (i < NT * K_OFFSETS) cnt2[i] = 0;
}

// (tile,k) CSR: entry = (local_o << 17) | in_idx  (6 + 17 bits).
// in_map indirection resolved at build time. XCD-partitioned over tile ranges
// so each group's counter/bucket lines live in ONE XCD's L2 (round-2 proven).
__global__ __launch_bounds__(256) void build_tk_kernel(
    const int* __restrict__ out_map, const int* __restrict__ in_map,
    int* __restrict__ cnt2, int* __restrict__ idx2) {
  const int grp = blockIdx.x & (CSR_GROUPS - 1);
  const int blk = blockIdx.x >> 3;
  const int tlo = grp * TPG;
  const int thi = (tlo + TPG < NT) ? (tlo + TPG) : NT;
  const int total4 = K_OFFSETS * N_PAIRS / 4;   // 337500
  for (int i4 = blk * 256 + (int)threadIdx.x; i4 < total4; i4 += CSR_BPG * 256) {
    int4 o4 = *(const int4*)&out_map[i4 * 4];
    int4 n4 = *(const int4*)&in_map[i4 * 4];
    int o[4] = {o4.x, o4.y, o4.z, o4.w};
    int n[4] = {n4.x, n4.y, n4.z, n4.w};
#pragma unroll
    for (int j = 0; j < 4; ++j) {
      int tt = o[j] >> 6;
      if (tt >= tlo && tt < thi) {
        int flat = i4 * 4 + j;
        int k = flat / N_PAIRS;
        int pos = atomicAdd(&cnt2[tt * K_OFFSETS + k], 1);
        if (pos < TK_CAP)
          idx2[(tt * K_OFFSETS + k) * TK_CAP + pos] = ((o[j] & 63) << 17) | n[j];
      }
    }
  }
}

// Fused conv+scatter v3. Block = 64-point tile, fp32 accum in LDS (33.8 KB only).
// Worklist of 32-entry k-tagged supertiles (round-4 verified); waves chew them
// with NO inner barriers. Per supertile: 8 scattered x-gather loads (the only
// multi-line-scattered VMEM left), then 32 B-frag loads each a CONSECUTIVE 1KB
// segment from fragment-line-ordered WF (this was the round-3/4 killer: the old
// layout made every B-load touch 16 scattered lines). MFMA mapping and ds_add
// scatter identical to the round-4-verified kernel.
__global__ __launch_bounds__(256, 3) void fused_conv_kernel(
    const unsigned short* __restrict__ xb, const unsigned short* __restrict__ wf,
    const int* __restrict__ cnt2, const int* __restrict__ idx2,
    const float* __restrict__ bias, const float* __restrict__ features,
    float* __restrict__ out, unsigned short* __restrict__ x1b, int layer) {
  __shared__ float accum[TILE * ACCW];          // 33,792 B
  __shared__ int ecnt[K_OFFSETS];
  __shared__ int stbase[K_OFFSETS + 1];
  __shared__ int stk[MAXST];

  const int t = blockIdx.x;
  const int tid = threadIdx.x;
  const int wave = tid >> 6;
  const int lane = tid & 63;
  const int l15 = lane & 15;
  const int kg = lane >> 4;

  for (int i = tid; i < TILE * ACCW; i += 256) accum[i] = 0.f;
  if (tid < K_OFFSETS) {
    int e = cnt2[t * K_OFFSETS + tid];
    ecnt[tid] = (e > TK_CAP) ? TK_CAP : e;
  }
  __syncthreads();
  if (tid == 0) {
    int run = 0;
    for (int k = 0; k < K_OFFSETS; ++k) {
      stbase[k] = run;
      run += (ecnt[k] + 31) >> 5;
    }
    stbase[K_OFFSETS] = run;
  }
  __syncthreads();
  if (tid < K_OFFSETS) {
    int s0 = stbase[tid];
    int nloc = stbase[tid + 1] - s0;
    for (int j = 0; j < nloc; ++j) stk[s0 + j] = (tid << 2) | j;
  }
  __syncthreads();
  const int nst = stbase[K_OFFSETS];

  for (int st = wave; st < nst; st += 4) {
    const int se = stk[st];
    const int k = se >> 2;
    const int r = se & 3;
    const int e = ecnt[k];
    const int bucket = (t * K_OFFSETS + k) * TK_CAP;
    const int i0 = r * 32 + l15;
    const int i1 = i0 + 16;
    const int ent0 = idx2[bucket + ((i0 < e) ? i0 : 0)];   // clamp: scatter predicated
    const int ent1 = idx2[bucket + ((i1 < e) ? i1 : 0)];
    const unsigned short* xrow0 = xb + (size_t)(ent0 & 0x1FFFF) * C + kg * 8;
    const unsigned short* xrow1 = xb + (size_t)(ent1 & 0x1FFFF) * C + kg * 8;

    short8 a0[4], a1[4];
#pragma unroll
    for (int kk = 0; kk < 4; ++kk) {                        // 8 scattered loads in flight
      a0[kk] = *(const short8*)(xrow0 + kk * 32);
      a1[kk] = *(const short8*)(xrow1 + kk * 32);
    }

    const unsigned short* wkf = wf + (size_t)k * (C * C) + lane * 8;
    floatx4 acc0[8], acc1[8];
#pragma unroll
    for (int nt = 0; nt < 8; ++nt) {
      acc0[nt] = (floatx4){0.f, 0.f, 0.f, 0.f};
      acc1[nt] = (floatx4){0.f, 0.f, 0.f, 0.f};
    }
#pragma unroll
    for (int kk = 0; kk < 4; ++kk) {
#pragma unroll
      for (int nt = 0; nt < 8; ++nt) {
        short8 bv = *(const short8*)(wkf + (kk * 8 + nt) * 512);  // 1KB coalesced
        acc0[nt] = __builtin_amdgcn_mfma_f32_16x16x32_bf16(a0[kk], bv, acc0[nt], 0, 0, 0);
        acc1[nt] = __builtin_amdgcn_mfma_f32_16x16x32_bf16(a1[kk], bv, acc1[nt], 0, 0, 0);
      }
    }

#pragma unroll
    for (int i = 0; i < 4; ++i) {
      const int sl = kg * 4 + i;
      const int le0 = __shfl(ent0, sl);
      const int le1 = __shfl(ent1, sl);
      const int ei0 = r * 32 + sl;
      const int ei1 = ei0 + 16;
      if (ei0 < e) {
        float* ar = &accum[(((unsigned int)le0) >> 17) * ACCW + l15];
#pragma unroll
        for (int nt = 0; nt < 8; ++nt) atomicAdd(ar + nt * 16, acc0[nt][i]);
      }
      if (ei1 < e) {
        float* ar = &accum[(((unsigned int)le1) >> 17) * ACCW + l15];
#pragma unroll
        for (int nt = 0; nt < 8; ++nt) atomicAdd(ar + nt * 16, acc1[nt][i]);
      }
    }
  }
  __syncthreads();

  // epilogue: col fixed per thread, 32 j-steps (round-4 verified)
  const int col = tid & 127;
  const float bv = bias[col];
  const int r0 = tid >> 7;
#pragma unroll 4
  for (int j = 0; j < TILE / 2; ++j) {
    int row = r0 + j * 2;
    int o = t * TILE + row;
    if (o < N_POINTS) {
      float v = accum[row * ACCW + col] + bv;
      if (layer == 0) {
        x1b[(size_t)o * C + col] = f2bf(fmaxf(v, 0.f));
      } else {
        out[(size_t)o * C + col] = v + features[(size_t)o * C + col];
      }
    }
  }
}

// ---------------- fallback (atomic path, small ws, natural WT) ----------------
__global__ __launch_bounds__(256) void mid_kernel(
    const float* __restrict__ features, const float* __restrict__ b1,
    float* __restrict__ out, unsigned short* __restrict__ x1b) {
  int i = (blockIdx.x * 256 + threadIdx.x) * 4;
  if (i >= N_POINTS * C) return;
  float4 y = *(const float4*)&out[i];
  ushort4 u;
  u.x = f2bf(fmaxf(y.x, 0.f));
  u.y = f2bf(fmaxf(y.y, 0.f));
  u.z = f2bf(fmaxf(y.z, 0.f));
  u.w = f2bf(fmaxf(y.w, 0.f));
  *(ushort4*)&x1b[i] = u;
  float4 f = *(const float4*)&features[i];
  float4 b = *(const float4*)&b1[i & 127];
  float4 o;
  o.x = f.x + b.x; o.y = f.y + b.y; o.z = f.z + b.z; o.w = f.w + b.w;
  *(float4*)&out[i] = o;
}

__global__ __launch_bounds__(256, 4) void conv_atomic_kernel(
    const unsigned short* __restrict__ xb, const unsigned short* __restrict__ wbt,
    const int* __restrict__ in_map, const int* __restrict__ out_map,
    float* __restrict__ out) {
  __shared__ unsigned short Wlds[C * WPAD];
  const int k = blockIdx.y;
  const int pairBase = blockIdx.x * 64;
  const int tid = threadIdx.x;
  const unsigned short* wk = wbt + k * C * C;
#pragma unroll
  for (int it = 0; it < 8; ++it) {
    int t = tid + it * 256;
    int row = t >> 4;
    int col = (t & 15) << 3;
    *(uint4*)&Wlds[row * WPAD + col] = *(const uint4*)&wk[row * C + col];
  }
  __syncthreads();
  const int wave = tid >> 6;
  const int lane = tid & 63;
  const int l15 = lane & 15;
  const int kg = lane >> 4;
  const int pair0 = pairBase + wave * 16;
  const int prA = pair0 + l15;
  const int inIdx = (prA < N_PAIRS) ? in_map[k * N_PAIRS + prA] : 0;
  const unsigned short* arow = xb + (size_t)inIdx * C + kg * 8;
  floatx4 acc[8];
#pragma unroll
  for (int nt = 0; nt < 8; ++nt) acc[nt] = (floatx4){0.f, 0.f, 0.f, 0.f};
#pragma unroll
  for (int kk = 0; kk < 4; ++kk) {
    short8 a = *(const short8*)(arow + kk * 32);
    const unsigned short* bbase = &Wlds[l15 * WPAD + kk * 32 + kg * 8];
#pragma unroll
    for (int nt = 0; nt < 8; ++nt) {
      short8 b = *(const short8*)(bbase + nt * 16 * WPAD);
      acc[nt] = __builtin_amdgcn_mfma_f32_16x16x32_bf16(a, b, acc[nt], 0, 0, 0);
    }
  }
#pragma unroll
  for (int i = 0; i < 4; ++i) {
    int pr = pair0 + kg * 4 + i;
    if (pr < N_PAIRS) {
      int oi = out_map[k * N_PAIRS + pr];
      float* orow = out + (size_t)oi * C + l15;
#pragma unroll
      for (int nt = 0; nt < 8; ++nt) atomicAdd(orow + nt * 16, acc[nt][i]);
    }
  }
}

extern "C" void kernel_launch(void* const* d_in, const int* in_sizes, int n_in,
                              void* d_out, int out_size, void* d_ws, size_t ws_size,
                              hipStream_t stream) {
  const float* features = (const float*)d_in[0];
  const int* in_map     = (const int*)d_in[1];
  const int* out_map    = (const int*)d_in[2];
  const float* W0       = (const float*)d_in[3];
  const float* b0       = (const float*)d_in[4];
  const float* W1       = (const float*)d_in[5];
  const float* b1       = (const float*)d_in[6];
  float* out = (float*)d_out;

  char* ws = (char*)d_ws;
  unsigned short* xb  = (unsigned short*)(ws);                  // 25,600,000
  unsigned short* x1b = (unsigned short*)(ws + 25600000);       // 25,600,000
  unsigned short* WT0 = (unsigned short*)(ws + 51200000);       //    884,736
  unsigned short* WT1 = (unsigned short*)(ws + 52084736);       //    884,736
  int* cnt2           = (int*)(ws + 52969472);                  //    168,832 (42201*4 padded)
  int* idx2           = (int*)(ws + 53138304);                  // 16,205,184 (42201*96*4)
  // end = 69,343,488

  const int use_fused = (ws_size >= 69343488ULL) ? 1 : 0;

  prep_w_kernel<<<(2 * K_OFFSETS * C * C + 255) / 256, 256, 0, stream>>>(
      W0, W1, WT0, WT1, use_fused);
  prep_x_kernel<<<(N_POINTS * C / 4 + 255) / 256, 256, 0, stream>>>(
      features, b0, xb, out, use_fused ? 0 : 1);

  if (use_fused) {
    zero_cnt2_kernel<<<(NT * K_OFFSETS + 255) / 256, 256, 0, stream>>>(cnt2);
    build_tk_kernel<<<CSR_GROUPS * CSR_BPG, 256, 0, stream>>>(out_map, in_map, cnt2, idx2);

    fused_conv_kernel<<<NT, 256, 0, stream>>>(
        xb, WT0, cnt2, idx2, b0, features, out, x1b, 0);
    fused_conv_kernel<<<NT, 256, 0, stream>>>(
        x1b, WT1, cnt2, idx2, b1, features, out, x1b, 1);
  } else {
    dim3 cgrid((N_PAIRS + 63) / 64, K_OFFSETS);
    conv_atomic_kernel<<<cgrid, 256, 0, stream>>>(xb, WT0, in_map, out_map, out);
    mid_kernel<<<(N_POINTS * C / 4 + 255) / 256, 256, 0, stream>>>(features, b1, out, x1b);
    conv_atomic_kernel<<<cgrid, 256, 0, stream>>>(x1b, WT1, in_map, out_map, out);
  }
}

// Round 6
// 672.509 us; speedup vs baseline: 4.3145x; 3.3465x over previous
//
#include <hip/hip_runtime.h>

#define N_POINTS 100000
#define N_PAIRS  50000
#define K_OFFSETS 27
#define C 128
#define WPAD 136   // 128 + 8 bf16 pad; LDS row stride 272B
#define CAP 48     // CSR bucket capacity; Poisson(13.5), P(>=48) ~ 3e-12 per point

// XCD-partitioned CSR build: group g = blockIdx.x % 8 (round-robin XCD dispatch
// heuristic) owns points [g*12500, (g+1)*12500). All counts/idxbuf writes for a
// point come from ONE XCD -> ~1MB write working set per L2, no line thrash.
#define CSR_GROUPS 8
#define CSR_BPG 128        // blocks per group; total grid = 1024

typedef __attribute__((ext_vector_type(8))) short short8;
typedef __attribute__((ext_vector_type(4))) float floatx4;

__device__ inline unsigned short f2bf(float f) {
  unsigned int u = __float_as_uint(f);
  return (unsigned short)((u + 0x7FFFu + ((u >> 16) & 1u)) >> 16);  // RNE
}
__device__ inline float bf2f(unsigned int lo16) {
  return __uint_as_float(lo16 << 16);
}

// WT[k][d*C + c] = bf16(W[k][c][d])  -- natural order for BOTH layers
__global__ __launch_bounds__(256) void prep_w_kernel(
    const float* __restrict__ W0, const float* __restrict__ W1,
    unsigned short* __restrict__ WT0, unsigned short* __restrict__ WT1) {
  int i = blockIdx.x * 256 + threadIdx.x;
  const int per = K_OFFSETS * C * C;
  if (i >= 2 * per) return;
  const float* W = (i < per) ? W0 : W1;
  unsigned short* WT = (i < per) ? WT0 : WT1;
  int r = (i < per) ? i : i - per;
  int k = r / (C * C);
  int q = r % (C * C);
  int d = q / C;
  int c = q % C;
  WT[k * C * C + d * C + c] = f2bf(W[k * C * C + c * C + d]);
}

// xb = bf16(features); out = broadcast(b0) only on the fallback path
__global__ __launch_bounds__(256) void prep_x_kernel(
    const float* __restrict__ features, const float* __restrict__ b0,
    unsigned short* __restrict__ xb, float* __restrict__ out, int write_out) {
  int i = (blockIdx.x * 256 + threadIdx.x) * 4;
  if (i >= N_POINTS * C) return;
  float4 f = *(const float4*)&features[i];
  ushort4 u;
  u.x = f2bf(f.x); u.y = f2bf(f.y); u.z = f2bf(f.z); u.w = f2bf(f.w);
  *(ushort4*)&xb[i] = u;
  if (write_out) {
    float4 b = *(const float4*)&b0[i & 127];
    *(float4*)&out[i] = b;
  }
}

__global__ __launch_bounds__(256) void zero_counts_kernel(int* __restrict__ counts) {
  int i = blockIdx.x * 256 + threadIdx.x;
  if (i < N_POINTS) counts[i] = 0;
}

// bucketed CSR of out_map: entry = (k<<16) | p  (p < 50000 < 2^16)
// v4: XCD-partitioned. Each group scans the whole out_map (L3-resident, cheap)
// but only emits entries for its own 1/8 point range, confining the scattered
// counts/idxbuf writes to a single XCD's L2 so lines fill before writeback.
__global__ __launch_bounds__(256) void build_csr_kernel(
    const int* __restrict__ out_map, int* __restrict__ counts, int* __restrict__ idxbuf) {
  const int grp = blockIdx.x & (CSR_GROUPS - 1);
  const int blk = blockIdx.x >> 3;
  const int lo = grp * (N_POINTS / CSR_GROUPS);
  const int hi = lo + (N_POINTS / CSR_GROUPS);
  const int total4 = K_OFFSETS * N_PAIRS / 4;   // 337500
  for (int i4 = blk * 256 + (int)threadIdx.x; i4 < total4; i4 += CSR_BPG * 256) {
    int4 o4 = *(const int4*)&out_map[i4 * 4];
    int o[4] = {o4.x, o4.y, o4.z, o4.w};
#pragma unroll
    for (int j = 0; j < 4; ++j) {
      if (o[j] >= lo && o[j] < hi) {
        int pos = atomicAdd(&counts[o[j]], 1);
        int flat = i4 * 4 + j;
        int k = flat / N_PAIRS;
        int p = flat - k * N_PAIRS;
        if (pos < CAP) idxbuf[o[j] * CAP + pos] = (k << 16) | p;
      }
    }
  }
}

// Phase A: msg[(k-k0)*P + p][slot j] = bf16((x[in_map[k,p]] @ W[k])[chan(j)])
// chan(j) = (j&7)*16 + (j>>3); slot order comes free from the MFMA D regs.
// v2: 128 pairs per block -- each wave runs 2 A-tiles against the same LDS W
// (halves W-staging per pair, 64 MFMA per wave per block).
__global__ __launch_bounds__(256, 4) void conv_msg_kernel(
    const unsigned short* __restrict__ xb, const unsigned short* __restrict__ wbt,
    const int* __restrict__ in_map, unsigned short* __restrict__ msg, int k0) {
  __shared__ unsigned short Wlds[C * WPAD];

  const int k = k0 + blockIdx.y;
  const int pairBase = blockIdx.x * 128;
  const int tid = threadIdx.x;

  const unsigned short* wk = wbt + k * C * C;
#pragma unroll
  for (int it = 0; it < 8; ++it) {
    int t = tid + it * 256;
    int row = t >> 4;
    int col = (t & 15) << 3;
    *(uint4*)&Wlds[row * WPAD + col] = *(const uint4*)&wk[row * C + col];
  }
  __syncthreads();

  const int wave = tid >> 6;
  const int lane = tid & 63;
  const int l15 = lane & 15;
  const int kg = lane >> 4;
  const int pair0 = pairBase + wave * 32;        // this wave's 32 pairs (2 tiles)

  const int prA0 = pair0 + l15;
  const int prA1 = pair0 + 16 + l15;
  const int inIdx0 = (prA0 < N_PAIRS) ? in_map[k * N_PAIRS + prA0] : 0;
  const int inIdx1 = (prA1 < N_PAIRS) ? in_map[k * N_PAIRS + prA1] : 0;
  const unsigned short* arow0 = xb + (size_t)inIdx0 * C + kg * 8;
  const unsigned short* arow1 = xb + (size_t)inIdx1 * C + kg * 8;

  floatx4 acc0[8], acc1[8];
#pragma unroll
  for (int nt = 0; nt < 8; ++nt) {
    acc0[nt] = (floatx4){0.f, 0.f, 0.f, 0.f};
    acc1[nt] = (floatx4){0.f, 0.f, 0.f, 0.f};
  }

#pragma unroll
  for (int kk = 0; kk < 4; ++kk) {
    short8 a0 = *(const short8*)(arow0 + kk * 32);
    short8 a1 = *(const short8*)(arow1 + kk * 32);
    const unsigned short* bbase = &Wlds[l15 * WPAD + kk * 32 + kg * 8];
#pragma unroll
    for (int nt = 0; nt < 8; ++nt) {
      short8 b = *(const short8*)(bbase + nt * 16 * WPAD);
      acc0[nt] = __builtin_amdgcn_mfma_f32_16x16x32_bf16(a0, b, acc0[nt], 0, 0, 0);
      acc1[nt] = __builtin_amdgcn_mfma_f32_16x16x32_bf16(a1, b, acc1[nt], 0, 0, 0);
    }
  }

  // store slot j = l15*8 + nt -> lane's 8 values contiguous (uint4, coalesced)
#pragma unroll
  for (int i = 0; i < 4; ++i) {
    int pr0 = pair0 + kg * 4 + i;
    if (pr0 < N_PAIRS) {
      unsigned short* row = msg + (size_t)(blockIdx.y * N_PAIRS + pr0) * C;
      uint4 v;
      v.x = (unsigned int)f2bf(acc0[0][i]) | ((unsigned int)f2bf(acc0[1][i]) << 16);
      v.y = (unsigned int)f2bf(acc0[2][i]) | ((unsigned int)f2bf(acc0[3][i]) << 16);
      v.z = (unsigned int)f2bf(acc0[4][i]) | ((unsigned int)f2bf(acc0[5][i]) << 16);
      v.w = (unsigned int)f2bf(acc0[6][i]) | ((unsigned int)f2bf(acc0[7][i]) << 16);
      *(uint4*)(row + l15 * 8) = v;
    }
    int pr1 = pair0 + 16 + kg * 4 + i;
    if (pr1 < N_PAIRS) {
      unsigned short* row = msg + (size_t)(blockIdx.y * N_PAIRS + pr1) * C;
      uint4 v;
      v.x = (unsigned int)f2bf(acc1[0][i]) | ((unsigned int)f2bf(acc1[1][i]) << 16);
      v.y = (unsigned int)f2bf(acc1[2][i]) | ((unsigned int)f2bf(acc1[3][i]) << 16);
      v.z = (unsigned int)f2bf(acc1[4][i]) | ((unsigned int)f2bf(acc1[5][i]) << 16);
      v.w = (unsigned int)f2bf(acc1[6][i]) | ((unsigned int)f2bf(acc1[7][i]) << 16);
      *(uint4*)(row + l15 * 8) = v;
    }
  }
}

// Phase B: one wave per output point; lane owns channels c0, c0+16 (slots 2*lane, 2*lane+1).
// idx list preloaded with ONE coalesced load, chunk-filtered and wave-compacted
// via ballot into LDS, then an unconditional unroll-4 loop of independent msg loads.
// Grid is exactly N_POINTS/4 blocks (100000 % 4 == 0): no early-return, barrier safe.
// init_mode: 0 = resume from out, 1 = bias (layer1 first), 2 = bias + residual (layer2 first)
// fin_mode:  0 = write out (fp32), 1 = relu -> x1b (bf16, layer1 last)
__global__ __launch_bounds__(256) void gather_kernel(
    const unsigned short* __restrict__ msg, const int* __restrict__ counts,
    const int* __restrict__ idxbuf, const float* __restrict__ bias,
    const float* __restrict__ features, float* __restrict__ out,
    unsigned short* __restrict__ x1b,
    int k0, int G, int init_mode, int fin_mode) {
  __shared__ int elds[4][64];
  const int wave = threadIdx.x >> 6;
  const int lane = threadIdx.x & 63;
  const int oi = blockIdx.x * 4 + wave;

  const int c0 = ((2 * lane) & 7) * 16 + (lane >> 2);
  const int c1 = c0 + 16;
  const size_t base = (size_t)oi * C;

  float a0, a1;
  if (init_mode == 1)      { a0 = bias[c0]; a1 = bias[c1]; }
  else if (init_mode == 2) { a0 = bias[c0] + features[base + c0];
                             a1 = bias[c1] + features[base + c1]; }
  else                     { a0 = out[base + c0]; a1 = out[base + c1]; }

  int cnt = counts[oi]; if (cnt > CAP) cnt = CAP;

  // one coalesced preload of this point's entry list (CAP=48 <= 64 lanes)
  int e_mine = (lane < cnt) ? idxbuf[oi * CAP + lane] : 0;
  bool ok = false;
  if (lane < cnt) {
    unsigned int rel = ((unsigned int)e_mine >> 16) - (unsigned int)k0;
    ok = rel < (unsigned int)G;
  }
  unsigned long long mask = __ballot(ok);
  int cnt2 = __popcll(mask);
  if (ok) {
    int pos = __popcll(mask & ((1ull << lane) - 1ull));
    unsigned int rel = ((unsigned int)e_mine >> 16) - (unsigned int)k0;
    elds[wave][pos] = (int)(rel * N_PAIRS + ((unsigned int)e_mine & 0xffffu));
  }
  __syncthreads();

  const unsigned short* mbase = msg + 2 * lane;
  int t = 0;
  for (; t + 4 <= cnt2; t += 4) {
    int f0 = elds[wave][t];
    int f1 = elds[wave][t + 1];
    int f2 = elds[wave][t + 2];
    int f3 = elds[wave][t + 3];
    unsigned int v0 = *(const unsigned int*)(mbase + (size_t)f0 * C);
    unsigned int v1 = *(const unsigned int*)(mbase + (size_t)f1 * C);
    unsigned int v2 = *(const unsigned int*)(mbase + (size_t)f2 * C);
    unsigned int v3 = *(const unsigned int*)(mbase + (size_t)f3 * C);
    a0 += bf2f(v0 & 0xffffu) + bf2f(v1 & 0xffffu) + bf2f(v2 & 0xffffu) + bf2f(v3 & 0xffffu);
    a1 += bf2f(v0 >> 16) + bf2f(v1 >> 16) + bf2f(v2 >> 16) + bf2f(v3 >> 16);
  }
  for (; t < cnt2; ++t) {
    int f0 = elds[wave][t];
    unsigned int v = *(const unsigned int*)(mbase + (size_t)f0 * C);
    a0 += bf2f(v & 0xffffu);
    a1 += bf2f(v >> 16);
  }

  if (fin_mode == 1) {
    x1b[base + c0] = f2bf(fmaxf(a0, 0.f));
    x1b[base + c1] = f2bf(fmaxf(a1, 0.f));
  } else {
    out[base + c0] = a0;
    out[base + c1] = a1;
  }
}

// ---------------- fallback (round-1 atomic path, <53 MB ws, natural WT1) ----------------
__global__ __launch_bounds__(256) void mid_kernel(
    const float* __restrict__ features, const float* __restrict__ b1,
    float* __restrict__ out, unsigned short* __restrict__ x1b) {
  int i = (blockIdx.x * 256 + threadIdx.x) * 4;
  if (i >= N_POINTS * C) return;
  float4 y = *(const float4*)&out[i];
  ushort4 u;
  u.x = f2bf(fmaxf(y.x, 0.f));
  u.y = f2bf(fmaxf(y.y, 0.f));
  u.z = f2bf(fmaxf(y.z, 0.f));
  u.w = f2bf(fmaxf(y.w, 0.f));
  *(ushort4*)&x1b[i] = u;
  float4 f = *(const float4*)&features[i];
  float4 b = *(const float4*)&b1[i & 127];
  float4 o;
  o.x = f.x + b.x; o.y = f.y + b.y; o.z = f.z + b.z; o.w = f.w + b.w;
  *(float4*)&out[i] = o;
}

__global__ __launch_bounds__(256, 4) void conv_atomic_kernel(
    const unsigned short* __restrict__ xb, const unsigned short* __restrict__ wbt,
    const int* __restrict__ in_map, const int* __restrict__ out_map,
    float* __restrict__ out) {
  __shared__ unsigned short Wlds[C * WPAD];
  const int k = blockIdx.y;
  const int pairBase = blockIdx.x * 64;
  const int tid = threadIdx.x;
  const unsigned short* wk = wbt + k * C * C;
#pragma unroll
  for (int it = 0; it < 8; ++it) {
    int t = tid + it * 256;
    int row = t >> 4;
    int col = (t & 15) << 3;
    *(uint4*)&Wlds[row * WPAD + col] = *(const uint4*)&wk[row * C + col];
  }
  __syncthreads();
  const int wave = tid >> 6;
  const int lane = tid & 63;
  const int l15 = lane & 15;
  const int kg = lane >> 4;
  const int pair0 = pairBase + wave * 16;
  const int prA = pair0 + l15;
  const int inIdx = (prA < N_PAIRS) ? in_map[k * N_PAIRS + prA] : 0;
  const unsigned short* arow = xb + (size_t)inIdx * C + kg * 8;
  floatx4 acc[8];
#pragma unroll
  for (int nt = 0; nt < 8; ++nt) acc[nt] = (floatx4){0.f, 0.f, 0.f, 0.f};
#pragma unroll
  for (int kk = 0; kk < 4; ++kk) {
    short8 a = *(const short8*)(arow + kk * 32);
    const unsigned short* bbase = &Wlds[l15 * WPAD + kk * 32 + kg * 8];
#pragma unroll
    for (int nt = 0; nt < 8; ++nt) {
      short8 b = *(const short8*)(bbase + nt * 16 * WPAD);
      acc[nt] = __builtin_amdgcn_mfma_f32_16x16x32_bf16(a, b, acc[nt], 0, 0, 0);
    }
  }
#pragma unroll
  for (int i = 0; i < 4; ++i) {
    int pr = pair0 + kg * 4 + i;
    if (pr < N_PAIRS) {
      int oi = out_map[k * N_PAIRS + pr];
      float* orow = out + (size_t)oi * C + l15;
#pragma unroll
      for (int nt = 0; nt < 8; ++nt) atomicAdd(orow + nt * 16, acc[nt][i]);
    }
  }
}

extern "C" void kernel_launch(void* const* d_in, const int* in_sizes, int n_in,
                              void* d_out, int out_size, void* d_ws, size_t ws_size,
                              hipStream_t stream) {
  const float* features = (const float*)d_in[0];
  const int* in_map     = (const int*)d_in[1];
  const int* out_map    = (const int*)d_in[2];
  const float* W0       = (const float*)d_in[3];
  const float* b0       = (const float*)d_in[4];
  const float* W1       = (const float*)d_in[5];
  const float* b1       = (const float*)d_in[6];
  float* out = (float*)d_out;

  char* ws = (char*)d_ws;
  unsigned short* xb  = (unsigned short*)(ws);                  // 25,600,000
  unsigned short* x1b = (unsigned short*)(ws + 25600000);       // 25,600,000
  unsigned short* WT0 = (unsigned short*)(ws + 51200000);       //    884,736
  unsigned short* WT1 = (unsigned short*)(ws + 52084736);       //    884,736
  int* counts         = (int*)(ws + 52969472);                  //    400,384
  int* idxbuf         = (int*)(ws + 53369856);                  // 19,200,000 (100000*CAP*4)
  unsigned short* msg = (unsigned short*)(ws + 72569856);       // G * 12,800,000

  const long long MSG_K_BYTES = (long long)N_PAIRS * C * 2;     // 12.8 MB per offset
  long long avail = (long long)ws_size - 72569856LL;
  int G = 0;
  if (avail >= MSG_K_BYTES) {
    long long g = avail / MSG_K_BYTES;
    G = (int)(g > K_OFFSETS ? K_OFFSETS : g);
  }

  prep_w_kernel<<<(2 * K_OFFSETS * C * C + 255) / 256, 256, 0, stream>>>(W0, W1, WT0, WT1);
  prep_x_kernel<<<(N_POINTS * C / 4 + 255) / 256, 256, 0, stream>>>(
      features, b0, xb, out, (G > 0) ? 0 : 1);

  if (G > 0) {
    zero_counts_kernel<<<(N_POINTS + 255) / 256, 256, 0, stream>>>(counts);
    build_csr_kernel<<<CSR_GROUPS * CSR_BPG, 256, 0, stream>>>(out_map, counts, idxbuf);

    const int nchunks = (K_OFFSETS + G - 1) / G;
    for (int layer = 0; layer < 2; ++layer) {
      const unsigned short* xin = layer ? x1b : xb;
      const unsigned short* wt  = layer ? WT1 : WT0;
      const float* bias         = layer ? b1  : b0;
      for (int c = 0; c < nchunks; ++c) {
        int k0 = c * G;
        int Gc = K_OFFSETS - k0 < G ? K_OFFSETS - k0 : G;
        dim3 cgrid((N_PAIRS + 127) / 128, Gc);
        conv_msg_kernel<<<cgrid, 256, 0, stream>>>(xin, wt, in_map, msg, k0);
        int init_mode = (c == 0) ? (layer ? 2 : 1) : 0;
        int fin_mode  = (layer == 0 && c == nchunks - 1) ? 1 : 0;
        gather_kernel<<<N_POINTS / 4, 256, 0, stream>>>(
            msg, counts, idxbuf, bias, features, out, x1b, k0, Gc, init_mode, fin_mode);
      }
    }
  } else {
    dim3 cgrid((N_PAIRS + 63) / 64, K_OFFSETS);
    conv_atomic_kernel<<<cgrid, 256, 0, stream>>>(xb, WT0, in_map, out_map, out);
    mid_kernel<<<(N_POINTS * C / 4 + 255) / 256, 256, 0, stream>>>(features, b1, out, x1b);
    conv_atomic_kernel<<<cgrid, 256, 0, stream>>>(x1b, WT1, in_map, out_map, out);
  }
}